// Round 6
// baseline (8677891.406 us; speedup 1.0000x reference)
//
#include <hip/hip_runtime.h>
#include <hip/hip_bf16.h>

#define B_ 32
#define T_ 512
#define E_ 256
#define H_ 512
#define L_ 50
#define V_ 50000
#define NBLK 32          // worker blocks (all on ONE XCD)
#define NGRID 256        // launched blocks; non-winners spin to keep clocks up

typedef __attribute__((ext_vector_type(8))) short short8;
typedef __attribute__((ext_vector_type(4))) float v4f;
typedef __attribute__((ext_vector_type(4))) int i4;
typedef unsigned long long u64;

__device__ __forceinline__ unsigned short f2bf(float f){
    union { float f; unsigned u; } v; v.f = f;
    unsigned u = v.u;
    u += 0x7fffu + ((u >> 16) & 1u);   // RNE
    return (unsigned short)(u >> 16);
}
// native-transcendental activations: v_exp_f32 + v_rcp_f32 (~1e-6 rel err, far
// below the bf16 rounding already in the h pipeline; validated absmax=0 r2-r4)
__device__ __forceinline__ float fastsig(float x){
    return __builtin_amdgcn_rcpf(1.0f + __expf(-x));
}
__device__ __forceinline__ float fasttanh(float x){
    return 1.0f - 2.0f * __builtin_amdgcn_rcpf(__expf(2.0f * x) + 1.0f);
}

__device__ __forceinline__ float qredmax(float v){
    v = fmaxf(v, __shfl_xor(v, 1, 64));
    v = fmaxf(v, __shfl_xor(v, 2, 64));
    v = fmaxf(v, __shfl_xor(v, 4, 64));
    v = fmaxf(v, __shfl_xor(v, 8, 64));
    return v;
}
__device__ __forceinline__ float qredsum(float v){
    v += __shfl_xor(v, 1, 64);
    v += __shfl_xor(v, 2, 64);
    v += __shfl_xor(v, 4, 64);
    v += __shfl_xor(v, 8, 64);
    return v;
}

// sc0-only memory ops: bypass L1, hit the XCD-shared L2 (intra-XCD coherent).
__device__ __forceinline__ i4 load16_sc0(const void* p){
    i4 r;
    asm volatile("global_load_dwordx4 %0, %1, off sc0" : "=v"(r) : "v"(p) : "memory");
    return r;
}
__device__ __forceinline__ void store8_sc0(void* p, u64 v){
    asm volatile("global_store_dwordx2 %0, %1, off sc0" : : "v"(p), "v"(v) : "memory");
}
__device__ __forceinline__ void store4_sc0(void* p, unsigned v){
    asm volatile("global_store_dword %0, %1, off sc0" : : "v"(p), "v"(v) : "memory");
}
__device__ __forceinline__ unsigned load4_sc0_wait(const void* p){
    unsigned r;
    asm volatile("global_load_dword %0, %1, off sc0\n\ts_waitcnt vmcnt(0)"
                 : "=v"(r) : "v"(p) : "memory");
    return r;
}
__device__ __forceinline__ unsigned load4_sc0_nowait(const void* p){
    unsigned r;
    asm volatile("global_load_dword %0, %1, off sc0" : "=v"(r) : "v"(p) : "memory");
    return r;
}
__device__ __forceinline__ void wait_vm0(){
    asm volatile("s_waitcnt vmcnt(0)" ::: "memory");
}

// ---------------------------------------------------------------- init + we->bf16 convert
__global__ void init_kernel(const float* __restrict__ projW,
                            const float* __restrict__ we,
                            float* __restrict__ out,
                            unsigned int* __restrict__ setup,   // [0]=winner, [1..8]=tickets, [64]=done
                            unsigned int* __restrict__ flags,   // [NBLK] monotonic step tags
                            unsigned short* __restrict__ h0,
                            unsigned short* __restrict__ Wt,
                            unsigned short* __restrict__ we_bf)
{
    const int i = blockIdx.x * 256 + threadIdx.x;
    if (i < 1024) setup[i] = 0u;
    if (i < NBLK) flags[i] = 0u;
    if (i == 0) out[0] = 0.f;
    if (i < B_ * H_) h0[i] = 0;                     // h_all step 0 = zeros
    if (i < 64 * H_){                               // Wt[c][k] = proj_W[k][c], bf16, pad c>=50 with 0
        const int c = i >> 9;
        const int k = i & 511;
        const float v = (c < L_) ? projW[k * L_ + c] : 0.f;
        Wt[i] = f2bf(v);
    }
    if (i < (V_ * E_) / 8){                         // bf16 embedding table (same RNE as before)
        const v4f* src = (const v4f*)(we + (size_t)i * 8);
        const v4f a = src[0], b = src[1];
        short8 o;
#pragma unroll
        for (int j = 0; j < 4; ++j){ o[j] = (short)f2bf(a[j]); o[4 + j] = (short)f2bf(b[j]); }
        *(short8*)(we_bf + (size_t)i * 8) = o;
    }
}

// ---------------------------------------------------------------- LSTM recurrence (cooperative, single-XCD)
// Protocol identical to round 4 (proven): monotonic dword block flags, lane<32
// sleep-poll, u64 shuffle-packed h stores, __syncthreads + single flag store.
// Round-6 schedule (fixes r5's exposed-xe-RT flaw):
//   top: poll-check (waits only pre-issued pollv, landed during tail)
//        -> issue h loads -> wait -> ISSUE xe(t+1) (RT hides under MFMA+gates)
//        -> 32 MFMA -> gates -> pack/store -> ack(drains xe too, landed)
//        -> syncthreads -> flag store -> PRE-ISSUE pollv -> 16 tail MFMA.
//  * CLOCK BOOST: non-winner blocks spin dense independent VALU FMAs until a
//    device-scope done flag (r3->r4 delta implied active XCD ~0.7GHz under
//    idle-chip DPM; busy XCDs should raise the clock for the serial chain).
//    Bounded: cap 1<<20 iters (~56ms), done-check every 32.
__global__ void __launch_bounds__(256, 1) lstm_kernel(
    const int* __restrict__ q, const int* __restrict__ lengths,
    const unsigned short* __restrict__ we_bf, const float* __restrict__ lstmW,
    const float* __restrict__ lstmB,
    unsigned short* __restrict__ h_all, unsigned int* __restrict__ flags,
    unsigned int* __restrict__ setup)
{
    const int tid  = threadIdx.x;

    __shared__ int s_role;
    if (tid == 0){
        int xcd;
        asm volatile("s_getreg_b32 %0, hwreg(HW_REG_XCC_ID)" : "=s"(xcd));
        xcd &= 7;
        unsigned tk = __hip_atomic_fetch_add(&setup[1 + xcd], 1u,
                                             __ATOMIC_RELAXED, __HIP_MEMORY_SCOPE_AGENT);
        int role = -1;
        if (tk < (unsigned)NBLK){
            if (tk == NBLK - 1){
                unsigned exp = 0u;
                __hip_atomic_compare_exchange_strong(&setup[0], &exp, (unsigned)(xcd + 1),
                    __ATOMIC_RELAXED, __ATOMIC_RELAXED, __HIP_MEMORY_SCOPE_AGENT);
            }
            unsigned w = 0u; int guard = 0;
            for (;;){
                w = __hip_atomic_load(&setup[0], __ATOMIC_RELAXED, __HIP_MEMORY_SCOPE_AGENT);
                if (w != 0u || ++guard > (1 << 24)) break;
                __builtin_amdgcn_s_sleep(2);
            }
            if (w == (unsigned)(xcd + 1)) role = (int)tk;
        }
        s_role = role;
    }
    __syncthreads();
    const int blk = s_role;          // worker slot 0..31, or -1

    if (blk < 0){
        // ---- clock-boost spinner: dense independent FMAs, exit on done flag.
        float a0 = 1.0f + (float)tid, a1 = 2.0f, a2 = 3.0f, a3 = 4.0f;
        for (int it = 0; it < (1 << 20); ++it){
#pragma unroll
            for (int j = 0; j < 16; ++j){
                a0 = __builtin_fmaf(a0, 0.9999999f, 1e-7f);
                a1 = __builtin_fmaf(a1, 0.9999999f, 1e-7f);
                a2 = __builtin_fmaf(a2, 0.9999999f, 1e-7f);
                a3 = __builtin_fmaf(a3, 0.9999999f, 1e-7f);
            }
            if ((it & 31) == 0 &&
                __hip_atomic_load(&setup[64], __ATOMIC_RELAXED, __HIP_MEMORY_SCOPE_AGENT))
                break;
        }
        asm volatile("" :: "v"(a0), "v"(a1), "v"(a2), "v"(a3));
        return;
    }

    const int wv   = tid >> 6;       // 0..3
    const int lane = tid & 63;
    const int nt = wv & 1, mpair = wv >> 1;   // n-half, m-tile pair
    const int l15 = lane & 15, quad = lane >> 4;

    // ---- A-operand mapping (lane&15 = m = z-col in tile; k = quad*8 + j)
    const int hcA0 = blk * 16 + (mpair * 2 + 0) * 4 + (l15 >> 2);
    const int hcA1 = blk * 16 + (mpair * 2 + 1) * 4 + (l15 >> 2);
    const int gA   = l15 & 3;
    const int colA0 = gA * H_ + hcA0;
    const int colA1 = gA * H_ + hcA1;

    short8 AW0[8], AW1[8], AH0[16], AH1[16];
#pragma unroll
    for (int kc = 0; kc < 8; ++kc){     // x-part rows 0..255
        short8 f0, f1;
#pragma unroll
        for (int j = 0; j < 8; ++j){
            const int r = kc * 32 + quad * 8 + j;
            f0[j] = (short)f2bf(lstmW[(size_t)r * 2048 + colA0]);
            f1[j] = (short)f2bf(lstmW[(size_t)r * 2048 + colA1]);
        }
        AW0[kc] = f0; AW1[kc] = f1;
    }
#pragma unroll
    for (int kc = 0; kc < 16; ++kc){    // h-part rows 256..767
        short8 f0, f1;
#pragma unroll
        for (int j = 0; j < 8; ++j){
            const int r = E_ + kc * 32 + quad * 8 + j;
            f0[j] = (short)f2bf(lstmW[(size_t)r * 2048 + colA0]);
            f1[j] = (short)f2bf(lstmW[(size_t)r * 2048 + colA1]);
        }
        AH0[kc] = f0; AH1[kc] = f1;
    }

    // ---- epilogue mapping (lane&15 = n = batch; D row quad*4+reg -> hc=quad, gate=reg)
    const int bE   = nt * 16 + l15;
    const int hcE0 = blk * 16 + (mpair * 2 + 0) * 4 + quad;
    const int hcE1 = blk * 16 + (mpair * 2 + 1) * 4 + quad;
    float bias0[4], bias1[4];
#pragma unroll
    for (int g = 0; g < 4; ++g){ bias0[g] = lstmB[g * H_ + hcE0]; bias1[g] = lstmB[g * H_ + hcE1]; }
    const int lenb = lengths[bE];

    float c0 = 0.f, c1 = 0.f, hp0 = 0.f, hp1 = 0.f;

    // pre-loop x-part for t=0 (cold path)
    v4f accX0 = { bias0[0], bias0[1], bias0[2], bias0[3] };
    v4f accX1 = { bias1[0], bias1[1], bias1[2], bias1[3] };
    {
        const int qv = q[bE * T_];
        const short8* wp = (const short8*)(we_bf + (size_t)qv * E_);
#pragma unroll
        for (int kc = 0; kc < 8; ++kc){
            const short8 eb = wp[kc * 4 + quad];
            accX0 = __builtin_amdgcn_mfma_f32_16x16x32_bf16(AW0[kc], eb, accX0, 0, 0, 0);
            accX1 = __builtin_amdgcn_mfma_f32_16x16x32_bf16(AW1[kc], eb, accX1, 0, 0, 0);
        }
    }

    int qnext = q[bE * T_ + 1];      // q for t+1 (prefetched one iter ahead)
    unsigned pollv = 0xFFFFFFFFu;    // pre-issued flag values (see loop end)

    for (int t = 0; t < T_; ++t){
        // (B) poll check: pollv was pre-issued after last flag store; its RT
        // overlapped the tail. Nothing else is outstanding here, so the wait
        // costs ~0. Fall back to the proven sleep-poll loop only on miss.
        if (t > 0){
            wait_vm0();
            if (__ballot(pollv >= (unsigned)t) != 0xFFFFFFFFFFFFFFFFull){
                int guard = 0;
                for (;;){
                    unsigned f = 0xFFFFFFFFu;
                    if (lane < NBLK) f = load4_sc0_wait(flags + lane);
                    if (__ballot(f >= (unsigned)t) == 0xFFFFFFFFFFFFFFFFull) break;
                    __builtin_amdgcn_s_sleep(1);
                    if (++guard > (1 << 17)) break;   // safety valve
                }
            }
        }

        // (C) all 16 h B-frag loads from L2 (sc0), ONE wait
        const unsigned short* hrow = h_all + (size_t)t * (B_ * H_) + (size_t)bE * H_;
        i4 hbuf[16];
#pragma unroll
        for (int kc = 0; kc < 16; ++kc)
            hbuf[kc] = load16_sc0(hrow + kc * 32 + quad * 8);
        wait_vm0();

        // (A) issue bf16 x-row loads for t+1 NOW: RT hides under the 32 MFMA +
        // gates below; drained (already landed) by (F)'s store-ack wait.
        short8 xe[8];
        {
            const short8* wp = (const short8*)(we_bf + (size_t)qnext * E_);
#pragma unroll
            for (int kc = 0; kc < 8; ++kc) xe[kc] = wp[kc * 4 + quad];
        }
        const int qnext2 = q[bE * T_ + ((t + 2 < T_) ? (t + 2) : (T_ - 1))];

        // (D) 32 MFMA in 4 independent chains (kc even/odd x 2 tiles)
        v4f a0e = accX0, a1e = accX1;
        v4f a0o = { 0.f, 0.f, 0.f, 0.f }, a1o = { 0.f, 0.f, 0.f, 0.f };
#pragma unroll
        for (int kc = 0; kc < 16; kc += 2){
            union { i4 i; short8 s; } cv0, cv1; cv0.i = hbuf[kc]; cv1.i = hbuf[kc + 1];
            a0e = __builtin_amdgcn_mfma_f32_16x16x32_bf16(AH0[kc],     cv0.s, a0e, 0, 0, 0);
            a1e = __builtin_amdgcn_mfma_f32_16x16x32_bf16(AH1[kc],     cv0.s, a1e, 0, 0, 0);
            a0o = __builtin_amdgcn_mfma_f32_16x16x32_bf16(AH0[kc + 1], cv1.s, a0o, 0, 0, 0);
            a1o = __builtin_amdgcn_mfma_f32_16x16x32_bf16(AH1[kc + 1], cv1.s, a1o, 0, 0, 0);
        }
        const v4f acc0 = a0e + a0o;
        const v4f acc1 = a1e + a1o;

        // (E) gates per tile: i,j,f,o = acc[0..3]; native exp/rcp
        const bool msk = (t < lenb);
        const float cn0 = c0 * fastsig(acc0[2] + 1.0f) + fastsig(acc0[0]) * fasttanh(acc0[1]);
        const float hn0 = fasttanh(cn0) * fastsig(acc0[3]);
        c0 = msk ? cn0 : c0;
        const float h20 = msk ? hn0 : hp0; hp0 = h20;
        const float cn1 = c1 * fastsig(acc1[2] + 1.0f) + fastsig(acc1[0]) * fasttanh(acc1[1]);
        const float hn1 = fasttanh(cn1) * fastsig(acc1[3]);
        c1 = msk ? cn1 : c1;
        const float h21 = msk ? hn1 : hp1; hp1 = h21;

        // (F) pack 4 hc per tile into u64; quad0 stores tile0, quad1 stores tile1
        const unsigned hv0 = f2bf(h20), hv1 = f2bf(h21);
        const int a0 = __shfl((int)hv0, l15, 64),      a1 = __shfl((int)hv0, l15 + 16, 64);
        const int a2 = __shfl((int)hv0, l15 + 32, 64), a3 = __shfl((int)hv0, l15 + 48, 64);
        const int b0 = __shfl((int)hv1, l15, 64),      b1 = __shfl((int)hv1, l15 + 16, 64);
        const int b2 = __shfl((int)hv1, l15 + 32, 64), b3 = __shfl((int)hv1, l15 + 48, 64);
        unsigned short* dstBase = h_all + (size_t)(t + 1) * (B_ * H_) + (size_t)bE * H_
                                + blk * 16 + mpair * 8;
        if (quad == 0){
            const u64 pk = (u64)(unsigned short)a0 | ((u64)(unsigned short)a1 << 16)
                         | ((u64)(unsigned short)a2 << 32) | ((u64)(unsigned short)a3 << 48);
            store8_sc0(dstBase, pk);
        } else if (quad == 1){
            const u64 pk = (u64)(unsigned short)b0 | ((u64)(unsigned short)b1 << 16)
                         | ((u64)(unsigned short)b2 << 32) | ((u64)(unsigned short)b3 << 48);
            store8_sc0(dstBase + 4, pk);
        }
        wait_vm0();                      // h stores committed (xe long landed)
        __syncthreads();                 // all waves of block done
        if (tid == 0)
            store4_sc0(&flags[blk], (unsigned)(t + 1));

        // pre-issue next step's flag poll: RT overlaps the tail below
        if (lane < NBLK) pollv = load4_sc0_nowait(flags + lane);

        // (G) tail (in notify slack): 16 MFMA on prefetched bf16 x-row
        if (t + 1 < T_){
            accX0 = (v4f){ bias0[0], bias0[1], bias0[2], bias0[3] };
            accX1 = (v4f){ bias1[0], bias1[1], bias1[2], bias1[3] };
#pragma unroll
            for (int kc = 0; kc < 8; ++kc){
                accX0 = __builtin_amdgcn_mfma_f32_16x16x32_bf16(AW0[kc], xe[kc], accX0, 0, 0, 0);
                accX1 = __builtin_amdgcn_mfma_f32_16x16x32_bf16(AW1[kc], xe[kc], accX1, 0, 0, 0);
            }
        }
        qnext = qnext2;
    }

    // signal spinners to exit (device scope — crosses XCD L2s)
    if (tid == 0)
        __hip_atomic_store(&setup[64], 1u, __ATOMIC_RELAXED, __HIP_MEMORY_SCOPE_AGENT);
}

// ---------------------------------------------------------------- projection + relu + log-softmax + xent
__global__ void __launch_bounds__(256) loss_kernel(
    const int* __restrict__ a, const int* __restrict__ lengths,
    const float* __restrict__ projB,
    const unsigned short* __restrict__ h_all,
    const unsigned short* __restrict__ Wt,
    float* __restrict__ out)
{
    const int tid = threadIdx.x;
    const int wv = tid >> 6, lane = tid & 63;
    const int l15 = lane & 15, quad = lane >> 4;
    const int wgid = blockIdx.x * 4 + wv;            // 0..1023
    const int row0 = wgid * 16;

    const int rowA = row0 + l15;
    const int bA = rowA >> 9, tA = rowA & 511;
    const unsigned short* hrow = h_all + ((size_t)(tA + 1) * B_ + bA) * H_;

    v4f acc[4] = { {0,0,0,0}, {0,0,0,0}, {0,0,0,0}, {0,0,0,0} };
#pragma unroll
    for (int kc = 0; kc < 16; ++kc){
        const short8 af = *(const short8*)(hrow + kc * 32 + quad * 8);
#pragma unroll
        for (int ntl = 0; ntl < 4; ++ntl){
            const short8 bf = *(const short8*)(Wt + (size_t)(ntl * 16 + l15) * H_ + kc * 32 + quad * 8);
            acc[ntl] = __builtin_amdgcn_mfma_f32_16x16x32_bf16(af, bf, acc[ntl], 0, 0, 0);
        }
    }

    float pb[4]; bool cv[4];
#pragma unroll
    for (int ntl = 0; ntl < 4; ++ntl){
        const int c = ntl * 16 + l15;
        cv[ntl] = (c < L_);
        pb[ntl] = cv[ntl] ? projB[c] : 0.f;
    }

#pragma unroll
    for (int r = 0; r < 4; ++r){
        const int row = row0 + quad * 4 + r;
        const int b = row >> 9, t = row & 511;
        const int len = lengths[b];
        const bool valid = (t < len);

        float lv[4];
#pragma unroll
        for (int ntl = 0; ntl < 4; ++ntl)
            lv[ntl] = fmaxf(acc[ntl][r] + pb[ntl], 0.f);   // relu(logits)

        float mx = -1e30f;
#pragma unroll
        for (int ntl = 0; ntl < 4; ++ntl) if (cv[ntl]) mx = fmaxf(mx, lv[ntl]);
        mx = qredmax(mx);
        float se = 0.f;
#pragma unroll
        for (int ntl = 0; ntl < 4; ++ntl) if (cv[ntl]) se += expf(lv[ntl] - mx);
        se = qredsum(se);
        const int lbl = a[row];
        float cand = 0.f;
#pragma unroll
        for (int ntl = 0; ntl < 4; ++ntl) if (ntl * 16 + l15 == lbl) cand = lv[ntl];
        const float llbl = qredsum(cand);

        if (valid && l15 == 0){
            const float xent = logf(se) + mx - llbl;      // -log_softmax[label]
            atomicAdd(out, xent / ((float)len * 32.0f));
        }
    }
}

// ---------------------------------------------------------------- launch
extern "C" void kernel_launch(void* const* d_in, const int* in_sizes, int n_in,
                              void* d_out, int out_size, void* d_ws, size_t ws_size,
                              hipStream_t stream)
{
    const int*   q   = (const int*)d_in[0];
    const int*   a   = (const int*)d_in[1];
    const int*   len = (const int*)d_in[2];
    const float* we  = (const float*)d_in[3];
    const float* lW  = (const float*)d_in[4];
    const float* lB  = (const float*)d_in[5];
    const float* pW  = (const float*)d_in[6];
    const float* pB  = (const float*)d_in[7];
    float* out = (float*)d_out;

    unsigned char* ws = (unsigned char*)d_ws;
    unsigned int*   setup = (unsigned int*)ws;                       // 4 KiB
    unsigned int*   flags = (unsigned int*)(ws + 4096);              // 32 dwords (4 KiB reserved)
    unsigned short* h_all = (unsigned short*)(ws + 8192);            // 513*32*512*2 B = 16.84 MB
    unsigned short* Wt    = (unsigned short*)(ws + 8192 + (size_t)(T_ + 1) * B_ * H_ * 2);  // 64 KiB
    unsigned short* we_bf = (unsigned short*)(ws + 8192 + (size_t)(T_ + 1) * B_ * H_ * 2 + 65536); // 25.6 MB

    init_kernel<<<dim3(6400), dim3(256), 0, stream>>>(pW, we, out, setup, flags, h_all, Wt, we_bf);

    {
        const int* q_ = q; const int* len_ = len; const unsigned short* we_ = we_bf;
        const float* lW_ = lW; const float* lB_ = lB;
        unsigned short* h_ = h_all; unsigned int* f_ = flags; unsigned int* s_ = setup;
        void* args[] = { (void*)&q_, (void*)&len_, (void*)&we_, (void*)&lW_,
                         (void*)&lB_, (void*)&h_, (void*)&f_, (void*)&s_ };
        hipLaunchCooperativeKernel((void*)lstm_kernel, dim3(NGRID), dim3(256),
                                   args, 0, stream);
    }

    loss_kernel<<<dim3(256), dim3(256), 0, stream>>>(a, len, pB, h_all, Wt, out);
}

// Round 8
// 4068230.078 us; speedup vs baseline: 2.1331x; 2.1331x over previous
//
#include <hip/hip_runtime.h>
#include <hip/hip_bf16.h>

#define B_ 32
#define T_ 512
#define E_ 256
#define H_ 512
#define L_ 50
#define V_ 50000
#define NBLK 32          // worker blocks (all on ONE XCD)
#define NGRID 256        // launched blocks; non-winners exit

typedef __attribute__((ext_vector_type(8))) short short8;
typedef __attribute__((ext_vector_type(4))) float v4f;
typedef __attribute__((ext_vector_type(4))) int i4;
typedef unsigned long long u64;

__device__ __forceinline__ unsigned short f2bf(float f){
    union { float f; unsigned u; } v; v.f = f;
    unsigned u = v.u;
    u += 0x7fffu + ((u >> 16) & 1u);   // RNE
    return (unsigned short)(u >> 16);
}
// native-transcendental activations: v_exp_f32 + v_rcp_f32 (~1e-6 rel err, far
// below the bf16 rounding already in the h pipeline; validated absmax=0 r2-r4)
__device__ __forceinline__ float fastsig(float x){
    return __builtin_amdgcn_rcpf(1.0f + __expf(-x));
}
__device__ __forceinline__ float fasttanh(float x){
    return 1.0f - 2.0f * __builtin_amdgcn_rcpf(__expf(2.0f * x) + 1.0f);
}

__device__ __forceinline__ float qredmax(float v){
    v = fmaxf(v, __shfl_xor(v, 1, 64));
    v = fmaxf(v, __shfl_xor(v, 2, 64));
    v = fmaxf(v, __shfl_xor(v, 4, 64));
    v = fmaxf(v, __shfl_xor(v, 8, 64));
    return v;
}
__device__ __forceinline__ float qredsum(float v){
    v += __shfl_xor(v, 1, 64);
    v += __shfl_xor(v, 2, 64);
    v += __shfl_xor(v, 4, 64);
    v += __shfl_xor(v, 8, 64);
    return v;
}

// sc0-only memory ops: bypass L1, hit the XCD-shared L2 (intra-XCD coherent).
__device__ __forceinline__ i4 load16_sc0(const void* p){
    i4 r;
    asm volatile("global_load_dwordx4 %0, %1, off sc0" : "=v"(r) : "v"(p) : "memory");
    return r;
}
__device__ __forceinline__ void store8_sc0(void* p, u64 v){
    asm volatile("global_store_dwordx2 %0, %1, off sc0" : : "v"(p), "v"(v) : "memory");
}
__device__ __forceinline__ void store4_sc0(void* p, unsigned v){
    asm volatile("global_store_dword %0, %1, off sc0" : : "v"(p), "v"(v) : "memory");
}
__device__ __forceinline__ unsigned load4_sc0_wait(const void* p){
    unsigned r;
    asm volatile("global_load_dword %0, %1, off sc0\n\ts_waitcnt vmcnt(0)"
                 : "=v"(r) : "v"(p) : "memory");
    return r;
}
__device__ __forceinline__ void wait_vm0(){
    asm volatile("s_waitcnt vmcnt(0)" ::: "memory");
}

// ---------------------------------------------------------------- init + we->bf16 convert
// grid 6400 x 256 = 1,638,400 threads; each converts 8 floats of word_embed.
__global__ void init_kernel(const float* __restrict__ projW,
                            const float* __restrict__ we,
                            float* __restrict__ out,
                            unsigned int* __restrict__ setup,   // [0]=winner, [1..8]=xcd tickets
                            unsigned int* __restrict__ flags,   // [NBLK] monotonic step tags
                            unsigned short* __restrict__ h0,
                            unsigned short* __restrict__ Wt,
                            unsigned short* __restrict__ we_bf)
{
    const int i = blockIdx.x * 256 + threadIdx.x;
    if (i < 1024) setup[i] = 0u;
    if (i < NBLK) flags[i] = 0u;
    if (i == 0) out[0] = 0.f;
    if (i < B_ * H_) h0[i] = 0;                     // h_all step 0 = zeros
    if (i < 64 * H_){                               // Wt[c][k] = proj_W[k][c], bf16, pad c>=50 with 0
        const int c = i >> 9;
        const int k = i & 511;
        const float v = (c < L_) ? projW[k * L_ + c] : 0.f;
        Wt[i] = f2bf(v);
    }
    if (i < (V_ * E_) / 8){                         // bf16 embedding table (same RNE as before)
        const v4f* src = (const v4f*)(we + (size_t)i * 8);
        const v4f a = src[0], b = src[1];
        short8 o;
#pragma unroll
        for (int j = 0; j < 4; ++j){ o[j] = (short)f2bf(a[j]); o[4 + j] = (short)f2bf(b[j]); }
        *(short8*)(we_bf + (size_t)i * 8) = o;
    }
}

// ---------------------------------------------------------------- LSTM recurrence (cooperative, single-XCD)
// Protocol byte-identical to the PROVEN round-4 kernel (2170us): monotonic
// dword block flags, lane<32 sleep-poll (entered every step), u64 shuffle-
// packed h stores, __syncthreads + single flag store. NO spinners, NO poll
// pre-issue (r5/r6 post-mortem). Single delta vs r4 (protocol-neutral):
// xe (embedding row) loads are issued AFTER the h-load wait instead of before
// the poll, so the poll's vmcnt(0) no longer drains the xe L3 round-trip
// (~400-700cy exposed in r4); the xe RT now hides under the 32-MFMA + gates
// phase and is drained by the store-ack wait.
// (r7 submitted this exact kernel; container failed twice = infra, resubmit.)
__global__ void __launch_bounds__(256, 1) lstm_kernel(
    const int* __restrict__ q, const int* __restrict__ lengths,
    const unsigned short* __restrict__ we_bf, const float* __restrict__ lstmW,
    const float* __restrict__ lstmB,
    unsigned short* __restrict__ h_all, unsigned int* __restrict__ flags,
    unsigned int* __restrict__ setup)
{
    const int tid  = threadIdx.x;

    __shared__ int s_role;
    if (tid == 0){
        int xcd;
        asm volatile("s_getreg_b32 %0, hwreg(HW_REG_XCC_ID)" : "=s"(xcd));
        xcd &= 7;
        unsigned tk = __hip_atomic_fetch_add(&setup[1 + xcd], 1u,
                                             __ATOMIC_RELAXED, __HIP_MEMORY_SCOPE_AGENT);
        int role = -1;
        if (tk < (unsigned)NBLK){
            if (tk == NBLK - 1){
                unsigned exp = 0u;
                __hip_atomic_compare_exchange_strong(&setup[0], &exp, (unsigned)(xcd + 1),
                    __ATOMIC_RELAXED, __ATOMIC_RELAXED, __HIP_MEMORY_SCOPE_AGENT);
            }
            unsigned w = 0u; int guard = 0;
            for (;;){
                w = __hip_atomic_load(&setup[0], __ATOMIC_RELAXED, __HIP_MEMORY_SCOPE_AGENT);
                if (w != 0u || ++guard > (1 << 24)) break;
                __builtin_amdgcn_s_sleep(2);
            }
            if (w == (unsigned)(xcd + 1)) role = (int)tk;
        }
        s_role = role;
    }
    __syncthreads();
    const int blk = s_role;          // worker slot 0..31, or -1
    if (blk < 0) return;

    const int wv   = tid >> 6;       // 0..3
    const int lane = tid & 63;
    const int nt = wv & 1, mpair = wv >> 1;   // n-half, m-tile pair
    const int l15 = lane & 15, quad = lane >> 4;

    // ---- A-operand mapping (lane&15 = m = z-col in tile; k = quad*8 + j)
    const int hcA0 = blk * 16 + (mpair * 2 + 0) * 4 + (l15 >> 2);
    const int hcA1 = blk * 16 + (mpair * 2 + 1) * 4 + (l15 >> 2);
    const int gA   = l15 & 3;
    const int colA0 = gA * H_ + hcA0;
    const int colA1 = gA * H_ + hcA1;

    short8 AW0[8], AW1[8], AH0[16], AH1[16];
#pragma unroll
    for (int kc = 0; kc < 8; ++kc){     // x-part rows 0..255
        short8 f0, f1;
#pragma unroll
        for (int j = 0; j < 8; ++j){
            const int r = kc * 32 + quad * 8 + j;
            f0[j] = (short)f2bf(lstmW[(size_t)r * 2048 + colA0]);
            f1[j] = (short)f2bf(lstmW[(size_t)r * 2048 + colA1]);
        }
        AW0[kc] = f0; AW1[kc] = f1;
    }
#pragma unroll
    for (int kc = 0; kc < 16; ++kc){    // h-part rows 256..767
        short8 f0, f1;
#pragma unroll
        for (int j = 0; j < 8; ++j){
            const int r = E_ + kc * 32 + quad * 8 + j;
            f0[j] = (short)f2bf(lstmW[(size_t)r * 2048 + colA0]);
            f1[j] = (short)f2bf(lstmW[(size_t)r * 2048 + colA1]);
        }
        AH0[kc] = f0; AH1[kc] = f1;
    }

    // ---- epilogue mapping (lane&15 = n = batch; D row quad*4+reg -> hc=quad, gate=reg)
    const int bE   = nt * 16 + l15;
    const int hcE0 = blk * 16 + (mpair * 2 + 0) * 4 + quad;
    const int hcE1 = blk * 16 + (mpair * 2 + 1) * 4 + quad;
    float bias0[4], bias1[4];
#pragma unroll
    for (int g = 0; g < 4; ++g){ bias0[g] = lstmB[g * H_ + hcE0]; bias1[g] = lstmB[g * H_ + hcE1]; }
    const int lenb = lengths[bE];

    float c0 = 0.f, c1 = 0.f, hp0 = 0.f, hp1 = 0.f;

    // pre-loop x-part for t=0 (cold path)
    v4f accX0 = { bias0[0], bias0[1], bias0[2], bias0[3] };
    v4f accX1 = { bias1[0], bias1[1], bias1[2], bias1[3] };
    {
        const int qv = q[bE * T_];
        const short8* wp = (const short8*)(we_bf + (size_t)qv * E_);
#pragma unroll
        for (int kc = 0; kc < 8; ++kc){
            const short8 eb = wp[kc * 4 + quad];
            accX0 = __builtin_amdgcn_mfma_f32_16x16x32_bf16(AW0[kc], eb, accX0, 0, 0, 0);
            accX1 = __builtin_amdgcn_mfma_f32_16x16x32_bf16(AW1[kc], eb, accX1, 0, 0, 0);
        }
    }

    int qnext = q[bE * T_ + 1];      // q for t+1 (prefetched one iter ahead)

    for (int t = 0; t < T_; ++t){
        // (B) poll 32 monotonic producer flags (lanes 0..31): f >= t means
        // h[t] is committed by that block. Flag region is 128B, stays L2-hot.
        // Nothing is outstanding here, so the poll wait is flag-RT only.
        if (t > 0){
            int guard = 0;
            for (;;){
                unsigned f = 0xFFFFFFFFu;
                if (lane < NBLK) f = load4_sc0_wait(flags + lane);
                if (__ballot(f >= (unsigned)t) == 0xFFFFFFFFFFFFFFFFull) break;
                __builtin_amdgcn_s_sleep(1);
                if (++guard > (1 << 17)) break;   // safety valve (never binding normally)
            }
        }

        // (C) all 16 h B-frag loads from L2 (sc0), ONE wait
        const unsigned short* hrow = h_all + (size_t)t * (B_ * H_) + (size_t)bE * H_;
        i4 hbuf[16];
#pragma unroll
        for (int kc = 0; kc < 16; ++kc)
            hbuf[kc] = load16_sc0(hrow + kc * 32 + quad * 8);
        wait_vm0();

        // (A) issue bf16 x-row loads for t+1 NOW: RT hides under the 32 MFMA +
        // gates below; drained (already landed) by (F)'s store-ack wait.
        short8 xe[8];
        {
            const short8* wp = (const short8*)(we_bf + (size_t)qnext * E_);
#pragma unroll
            for (int kc = 0; kc < 8; ++kc) xe[kc] = wp[kc * 4 + quad];
        }
        const int qnext2 = q[bE * T_ + ((t + 2 < T_) ? (t + 2) : (T_ - 1))];

        // (D) 32 MFMA in 4 independent chains (kc even/odd x 2 tiles)
        v4f a0e = accX0, a1e = accX1;
        v4f a0o = { 0.f, 0.f, 0.f, 0.f }, a1o = { 0.f, 0.f, 0.f, 0.f };
#pragma unroll
        for (int kc = 0; kc < 16; kc += 2){
            union { i4 i; short8 s; } cv0, cv1; cv0.i = hbuf[kc]; cv1.i = hbuf[kc + 1];
            a0e = __builtin_amdgcn_mfma_f32_16x16x32_bf16(AH0[kc],     cv0.s, a0e, 0, 0, 0);
            a1e = __builtin_amdgcn_mfma_f32_16x16x32_bf16(AH1[kc],     cv0.s, a1e, 0, 0, 0);
            a0o = __builtin_amdgcn_mfma_f32_16x16x32_bf16(AH0[kc + 1], cv1.s, a0o, 0, 0, 0);
            a1o = __builtin_amdgcn_mfma_f32_16x16x32_bf16(AH1[kc + 1], cv1.s, a1o, 0, 0, 0);
        }
        const v4f acc0 = a0e + a0o;
        const v4f acc1 = a1e + a1o;

        // (E) gates per tile: i,j,f,o = acc[0..3]; native exp/rcp
        const bool msk = (t < lenb);
        const float cn0 = c0 * fastsig(acc0[2] + 1.0f) + fastsig(acc0[0]) * fasttanh(acc0[1]);
        const float hn0 = fasttanh(cn0) * fastsig(acc0[3]);
        c0 = msk ? cn0 : c0;
        const float h20 = msk ? hn0 : hp0; hp0 = h20;
        const float cn1 = c1 * fastsig(acc1[2] + 1.0f) + fastsig(acc1[0]) * fasttanh(acc1[1]);
        const float hn1 = fasttanh(cn1) * fastsig(acc1[3]);
        c1 = msk ? cn1 : c1;
        const float h21 = msk ? hn1 : hp1; hp1 = h21;

        // (F) pack 4 hc per tile into u64; quad0 stores tile0, quad1 stores tile1
        const unsigned hv0 = f2bf(h20), hv1 = f2bf(h21);
        const int a0 = __shfl((int)hv0, l15, 64),      a1 = __shfl((int)hv0, l15 + 16, 64);
        const int a2 = __shfl((int)hv0, l15 + 32, 64), a3 = __shfl((int)hv0, l15 + 48, 64);
        const int b0 = __shfl((int)hv1, l15, 64),      b1 = __shfl((int)hv1, l15 + 16, 64);
        const int b2 = __shfl((int)hv1, l15 + 32, 64), b3 = __shfl((int)hv1, l15 + 48, 64);
        unsigned short* dstBase = h_all + (size_t)(t + 1) * (B_ * H_) + (size_t)bE * H_
                                + blk * 16 + mpair * 8;
        if (quad == 0){
            const u64 pk = (u64)(unsigned short)a0 | ((u64)(unsigned short)a1 << 16)
                         | ((u64)(unsigned short)a2 << 32) | ((u64)(unsigned short)a3 << 48);
            store8_sc0(dstBase, pk);
        } else if (quad == 1){
            const u64 pk = (u64)(unsigned short)b0 | ((u64)(unsigned short)b1 << 16)
                         | ((u64)(unsigned short)b2 << 32) | ((u64)(unsigned short)b3 << 48);
            store8_sc0(dstBase + 4, pk);
        }
        wait_vm0();                      // h stores committed (xe long landed)
        __syncthreads();                 // all waves of block done
        if (tid == 0)
            store4_sc0(&flags[blk], (unsigned)(t + 1));

        // (G) tail (in notify slack): 16 MFMA on prefetched bf16 x-row
        if (t + 1 < T_){
            accX0 = (v4f){ bias0[0], bias0[1], bias0[2], bias0[3] };
            accX1 = (v4f){ bias1[0], bias1[1], bias1[2], bias1[3] };
#pragma unroll
            for (int kc = 0; kc < 8; ++kc){
                accX0 = __builtin_amdgcn_mfma_f32_16x16x32_bf16(AW0[kc], xe[kc], accX0, 0, 0, 0);
                accX1 = __builtin_amdgcn_mfma_f32_16x16x32_bf16(AW1[kc], xe[kc], accX1, 0, 0, 0);
            }
        }
        qnext = qnext2;
    }
}

// ---------------------------------------------------------------- projection + relu + log-softmax + xent
__global__ void __launch_bounds__(256) loss_kernel(
    const int* __restrict__ a, const int* __restrict__ lengths,
    const float* __restrict__ projB,
    const unsigned short* __restrict__ h_all,
    const unsigned short* __restrict__ Wt,
    float* __restrict__ out)
{
    const int tid = threadIdx.x;
    const int wv = tid >> 6, lane = tid & 63;
    const int l15 = lane & 15, quad = lane >> 4;
    const int wgid = blockIdx.x * 4 + wv;            // 0..1023
    const int row0 = wgid * 16;

    const int rowA = row0 + l15;
    const int bA = rowA >> 9, tA = rowA & 511;
    const unsigned short* hrow = h_all + ((size_t)(tA + 1) * B_ + bA) * H_;

    v4f acc[4] = { {0,0,0,0}, {0,0,0,0}, {0,0,0,0}, {0,0,0,0} };
#pragma unroll
    for (int kc = 0; kc < 16; ++kc){
        const short8 af = *(const short8*)(hrow + kc * 32 + quad * 8);
#pragma unroll
        for (int ntl = 0; ntl < 4; ++ntl){
            const short8 bf = *(const short8*)(Wt + (size_t)(ntl * 16 + l15) * H_ + kc * 32 + quad * 8);
            acc[ntl] = __builtin_amdgcn_mfma_f32_16x16x32_bf16(af, bf, acc[ntl], 0, 0, 0);
        }
    }

    float pb[4]; bool cv[4];
#pragma unroll
    for (int ntl = 0; ntl < 4; ++ntl){
        const int c = ntl * 16 + l15;
        cv[ntl] = (c < L_);
        pb[ntl] = cv[ntl] ? projB[c] : 0.f;
    }

#pragma unroll
    for (int r = 0; r < 4; ++r){
        const int row = row0 + quad * 4 + r;
        const int b = row >> 9, t = row & 511;
        const int len = lengths[b];
        const bool valid = (t < len);

        float lv[4];
#pragma unroll
        for (int ntl = 0; ntl < 4; ++ntl)
            lv[ntl] = fmaxf(acc[ntl][r] + pb[ntl], 0.f);   // relu(logits)

        float mx = -1e30f;
#pragma unroll
        for (int ntl = 0; ntl < 4; ++ntl) if (cv[ntl]) mx = fmaxf(mx, lv[ntl]);
        mx = qredmax(mx);
        float se = 0.f;
#pragma unroll
        for (int ntl = 0; ntl < 4; ++ntl) if (cv[ntl]) se += expf(lv[ntl] - mx);
        se = qredsum(se);
        const int lbl = a[row];
        float cand = 0.f;
#pragma unroll
        for (int ntl = 0; ntl < 4; ++ntl) if (ntl * 16 + l15 == lbl) cand = lv[ntl];
        const float llbl = qredsum(cand);

        if (valid && l15 == 0){
            const float xent = logf(se) + mx - llbl;      // -log_softmax[label]
            atomicAdd(out, xent / ((float)len * 32.0f));
        }
    }
}

// ---------------------------------------------------------------- launch
extern "C" void kernel_launch(void* const* d_in, const int* in_sizes, int n_in,
                              void* d_out, int out_size, void* d_ws, size_t ws_size,
                              hipStream_t stream)
{
    const int*   q   = (const int*)d_in[0];
    const int*   a   = (const int*)d_in[1];
    const int*   len = (const int*)d_in[2];
    const float* we  = (const float*)d_in[3];
    const float* lW  = (const float*)d_in[4];
    const float* lB  = (const float*)d_in[5];
    const float* pW  = (const float*)d_in[6];
    const float* pB  = (const float*)d_in[7];
    float* out = (float*)d_out;

    unsigned char* ws = (unsigned char*)d_ws;
    unsigned int*   setup = (unsigned int*)ws;                       // 4 KiB
    unsigned int*   flags = (unsigned int*)(ws + 4096);              // 32 dwords (4 KiB reserved)
    unsigned short* h_all = (unsigned short*)(ws + 8192);            // 513*32*512*2 B = 16.84 MB
    unsigned short* Wt    = (unsigned short*)(ws + 8192 + (size_t)(T_ + 1) * B_ * H_ * 2);  // 64 KiB
    unsigned short* we_bf = (unsigned short*)(ws + 8192 + (size_t)(T_ + 1) * B_ * H_ * 2 + 65536); // 25.6 MB

    init_kernel<<<dim3(6400), dim3(256), 0, stream>>>(pW, we, out, setup, flags, h_all, Wt, we_bf);

    {
        const int* q_ = q; const int* len_ = len; const unsigned short* we_ = we_bf;
        const float* lW_ = lW; const float* lB_ = lB;
        unsigned short* h_ = h_all; unsigned int* f_ = flags; unsigned int* s_ = setup;
        void* args[] = { (void*)&q_, (void*)&len_, (void*)&we_, (void*)&lW_,
                         (void*)&lB_, (void*)&h_, (void*)&f_, (void*)&s_ };
        hipLaunchCooperativeKernel((void*)lstm_kernel, dim3(NGRID), dim3(256),
                                   args, 0, stream);
    }

    loss_kernel<<<dim3(256), dim3(256), 0, stream>>>(a, len, pB, h_all, Wt, out);
}

// Round 9
// 2425.273 us; speedup vs baseline: 3578.1089x; 1677.4317x over previous
//
#include <hip/hip_runtime.h>
#include <hip/hip_bf16.h>

#define B_ 32
#define T_ 512
#define E_ 256
#define H_ 512
#define L_ 50
#define V_ 50000
#define NBLK 32          // worker blocks (placement-independent protocol)
#define NGRID 32         // exactly the workers — no election, no spinners

typedef __attribute__((ext_vector_type(8))) short short8;
typedef __attribute__((ext_vector_type(4))) float v4f;
typedef __attribute__((ext_vector_type(4))) int i4;
typedef unsigned long long u64;

__device__ __forceinline__ unsigned short f2bf(float f){
    union { float f; unsigned u; } v; v.f = f;
    unsigned u = v.u;
    u += 0x7fffu + ((u >> 16) & 1u);   // RNE
    return (unsigned short)(u >> 16);
}
// native-transcendental activations: v_exp_f32 + v_rcp_f32 (~1e-6 rel err, far
// below the bf16 rounding already in the h pipeline; validated absmax=0 r2-r4)
__device__ __forceinline__ float fastsig(float x){
    return __builtin_amdgcn_rcpf(1.0f + __expf(-x));
}
__device__ __forceinline__ float fasttanh(float x){
    return 1.0f - 2.0f * __builtin_amdgcn_rcpf(__expf(2.0f * x) + 1.0f);
}

__device__ __forceinline__ float qredmax(float v){
    v = fmaxf(v, __shfl_xor(v, 1, 64));
    v = fmaxf(v, __shfl_xor(v, 2, 64));
    v = fmaxf(v, __shfl_xor(v, 4, 64));
    v = fmaxf(v, __shfl_xor(v, 8, 64));
    return v;
}
__device__ __forceinline__ float qredsum(float v){
    v += __shfl_xor(v, 1, 64);
    v += __shfl_xor(v, 2, 64);
    v += __shfl_xor(v, 4, 64);
    v += __shfl_xor(v, 8, 64);
    return v;
}

// DEVICE-coherent memory ops: sc0 sc1 = bypass L1 AND L2, coherence point is
// the MALL (gfx94x mapping of old glc+slc). Placement-independent: works no
// matter which XCDs the worker blocks land on. (r6/r8 post-mortem: sc0-only
// loads FILL the local L2, so cross-XCD consumers spin on a stale cached flag
// line until capacity eviction -> ms-scale steps with correct results.)
__device__ __forceinline__ i4 load16_dev(const void* p){
    i4 r;
    asm volatile("global_load_dwordx4 %0, %1, off sc0 sc1" : "=v"(r) : "v"(p) : "memory");
    return r;
}
__device__ __forceinline__ void store8_dev(void* p, u64 v){
    asm volatile("global_store_dwordx2 %0, %1, off sc0 sc1" : : "v"(p), "v"(v) : "memory");
}
__device__ __forceinline__ void store4_dev(void* p, unsigned v){
    asm volatile("global_store_dword %0, %1, off sc0 sc1" : : "v"(p), "v"(v) : "memory");
}
__device__ __forceinline__ unsigned load4_dev_wait(const void* p){
    unsigned r;
    asm volatile("global_load_dword %0, %1, off sc0 sc1\n\ts_waitcnt vmcnt(0)"
                 : "=v"(r) : "v"(p) : "memory");
    return r;
}
__device__ __forceinline__ void wait_vm0(){
    asm volatile("s_waitcnt vmcnt(0)" ::: "memory");
}

// ---------------------------------------------------------------- init + we->bf16 convert
// grid 6400 x 256 = 1,638,400 threads; each converts 8 floats of word_embed.
__global__ void init_kernel(const float* __restrict__ projW,
                            const float* __restrict__ we,
                            float* __restrict__ out,
                            unsigned int* __restrict__ setup,   // reserved (unused this round)
                            unsigned int* __restrict__ flags,   // [NBLK] monotonic step tags
                            unsigned short* __restrict__ h0,
                            unsigned short* __restrict__ Wt,
                            unsigned short* __restrict__ we_bf)
{
    const int i = blockIdx.x * 256 + threadIdx.x;
    if (i < 1024) setup[i] = 0u;
    if (i < NBLK) flags[i] = 0u;
    if (i == 0) out[0] = 0.f;
    if (i < B_ * H_) h0[i] = 0;                     // h_all step 0 = zeros
    if (i < 64 * H_){                               // Wt[c][k] = proj_W[k][c], bf16, pad c>=50 with 0
        const int c = i >> 9;
        const int k = i & 511;
        const float v = (c < L_) ? projW[k * L_ + c] : 0.f;
        Wt[i] = f2bf(v);
    }
    if (i < (V_ * E_) / 8){                         // bf16 embedding table (same RNE as before)
        const v4f* src = (const v4f*)(we + (size_t)i * 8);
        const v4f a = src[0], b = src[1];
        short8 o;
#pragma unroll
        for (int j = 0; j < 4; ++j){ o[j] = (short)f2bf(a[j]); o[4 + j] = (short)f2bf(b[j]); }
        *(short8*)(we_bf + (size_t)i * 8) = o;
    }
}

// ---------------------------------------------------------------- LSTM recurrence (cooperative, device-coherent)
// Round-9 restructure for PLACEMENT ROBUSTNESS:
//  * exactly 32 blocks launched, blk = blockIdx.x — the XCC_ID election is
//    GONE (it was the prime suspect for r6/r8: if workers are not truly
//    L2-mates, sc0-only flags/h are invisible until eviction).
//  * all h-exchange and flag ops are sc0 sc1 (MALL-coherent, works for any
//    block placement). Ordering unchanged: h stores -> vmcnt0 (MALL acks) ->
//    __syncthreads -> flag store; consumer: flag poll -> h loads.
//  * schedule otherwise identical to r4/r8: monotonic dword flags, lane<32
//    sleep-poll, u64 shuffle-packed h stores, xe issued after the h-wait
//    (hides its RT under MFMA+gates; drained by the store-ack wait).
__global__ void __launch_bounds__(256, 1) lstm_kernel(
    const int* __restrict__ q, const int* __restrict__ lengths,
    const unsigned short* __restrict__ we_bf, const float* __restrict__ lstmW,
    const float* __restrict__ lstmB,
    unsigned short* __restrict__ h_all, unsigned int* __restrict__ flags)
{
    const int tid  = threadIdx.x;
    const int blk  = blockIdx.x;     // worker slot 0..31

    const int wv   = tid >> 6;       // 0..3
    const int lane = tid & 63;
    const int nt = wv & 1, mpair = wv >> 1;   // n-half, m-tile pair
    const int l15 = lane & 15, quad = lane >> 4;

    // ---- A-operand mapping (lane&15 = m = z-col in tile; k = quad*8 + j)
    const int hcA0 = blk * 16 + (mpair * 2 + 0) * 4 + (l15 >> 2);
    const int hcA1 = blk * 16 + (mpair * 2 + 1) * 4 + (l15 >> 2);
    const int gA   = l15 & 3;
    const int colA0 = gA * H_ + hcA0;
    const int colA1 = gA * H_ + hcA1;

    short8 AW0[8], AW1[8], AH0[16], AH1[16];
#pragma unroll
    for (int kc = 0; kc < 8; ++kc){     // x-part rows 0..255
        short8 f0, f1;
#pragma unroll
        for (int j = 0; j < 8; ++j){
            const int r = kc * 32 + quad * 8 + j;
            f0[j] = (short)f2bf(lstmW[(size_t)r * 2048 + colA0]);
            f1[j] = (short)f2bf(lstmW[(size_t)r * 2048 + colA1]);
        }
        AW0[kc] = f0; AW1[kc] = f1;
    }
#pragma unroll
    for (int kc = 0; kc < 16; ++kc){    // h-part rows 256..767
        short8 f0, f1;
#pragma unroll
        for (int j = 0; j < 8; ++j){
            const int r = E_ + kc * 32 + quad * 8 + j;
            f0[j] = (short)f2bf(lstmW[(size_t)r * 2048 + colA0]);
            f1[j] = (short)f2bf(lstmW[(size_t)r * 2048 + colA1]);
        }
        AH0[kc] = f0; AH1[kc] = f1;
    }

    // ---- epilogue mapping (lane&15 = n = batch; D row quad*4+reg -> hc=quad, gate=reg)
    const int bE   = nt * 16 + l15;
    const int hcE0 = blk * 16 + (mpair * 2 + 0) * 4 + quad;
    const int hcE1 = blk * 16 + (mpair * 2 + 1) * 4 + quad;
    float bias0[4], bias1[4];
#pragma unroll
    for (int g = 0; g < 4; ++g){ bias0[g] = lstmB[g * H_ + hcE0]; bias1[g] = lstmB[g * H_ + hcE1]; }
    const int lenb = lengths[bE];

    float c0 = 0.f, c1 = 0.f, hp0 = 0.f, hp1 = 0.f;

    // pre-loop x-part for t=0 (cold path)
    v4f accX0 = { bias0[0], bias0[1], bias0[2], bias0[3] };
    v4f accX1 = { bias1[0], bias1[1], bias1[2], bias1[3] };
    {
        const int qv = q[bE * T_];
        const short8* wp = (const short8*)(we_bf + (size_t)qv * E_);
#pragma unroll
        for (int kc = 0; kc < 8; ++kc){
            const short8 eb = wp[kc * 4 + quad];
            accX0 = __builtin_amdgcn_mfma_f32_16x16x32_bf16(AW0[kc], eb, accX0, 0, 0, 0);
            accX1 = __builtin_amdgcn_mfma_f32_16x16x32_bf16(AW1[kc], eb, accX1, 0, 0, 0);
        }
    }

    int qnext = q[bE * T_ + 1];      // q for t+1 (prefetched one iter ahead)

    for (int t = 0; t < T_; ++t){
        // (B) poll 32 monotonic producer flags (lanes 0..31): f >= t means
        // h[t] is committed at the MALL by that block. sc0 sc1 loads are
        // always fresh (no local-L2 staleness regardless of placement).
        if (t > 0){
            int guard = 0;
            for (;;){
                unsigned f = 0xFFFFFFFFu;
                if (lane < NBLK) f = load4_dev_wait(flags + lane);
                if (__ballot(f >= (unsigned)t) == 0xFFFFFFFFFFFFFFFFull) break;
                __builtin_amdgcn_s_sleep(1);
                if (++guard > (1 << 16)) break;   // safety valve (never binding normally)
            }
        }

        // (C) all 16 h B-frag loads from the MALL, ONE wait
        const unsigned short* hrow = h_all + (size_t)t * (B_ * H_) + (size_t)bE * H_;
        i4 hbuf[16];
#pragma unroll
        for (int kc = 0; kc < 16; ++kc)
            hbuf[kc] = load16_dev(hrow + kc * 32 + quad * 8);
        wait_vm0();

        // (A) issue bf16 x-row loads for t+1 NOW (plain cached loads): RT
        // hides under the 32 MFMA + gates below; drained by (F)'s ack wait.
        short8 xe[8];
        {
            const short8* wp = (const short8*)(we_bf + (size_t)qnext * E_);
#pragma unroll
            for (int kc = 0; kc < 8; ++kc) xe[kc] = wp[kc * 4 + quad];
        }
        const int qnext2 = q[bE * T_ + ((t + 2 < T_) ? (t + 2) : (T_ - 1))];

        // (D) 32 MFMA in 4 independent chains (kc even/odd x 2 tiles)
        v4f a0e = accX0, a1e = accX1;
        v4f a0o = { 0.f, 0.f, 0.f, 0.f }, a1o = { 0.f, 0.f, 0.f, 0.f };
#pragma unroll
        for (int kc = 0; kc < 16; kc += 2){
            union { i4 i; short8 s; } cv0, cv1; cv0.i = hbuf[kc]; cv1.i = hbuf[kc + 1];
            a0e = __builtin_amdgcn_mfma_f32_16x16x32_bf16(AH0[kc],     cv0.s, a0e, 0, 0, 0);
            a1e = __builtin_amdgcn_mfma_f32_16x16x32_bf16(AH1[kc],     cv0.s, a1e, 0, 0, 0);
            a0o = __builtin_amdgcn_mfma_f32_16x16x32_bf16(AH0[kc + 1], cv1.s, a0o, 0, 0, 0);
            a1o = __builtin_amdgcn_mfma_f32_16x16x32_bf16(AH1[kc + 1], cv1.s, a1o, 0, 0, 0);
        }
        const v4f acc0 = a0e + a0o;
        const v4f acc1 = a1e + a1o;

        // (E) gates per tile: i,j,f,o = acc[0..3]; native exp/rcp
        const bool msk = (t < lenb);
        const float cn0 = c0 * fastsig(acc0[2] + 1.0f) + fastsig(acc0[0]) * fasttanh(acc0[1]);
        const float hn0 = fasttanh(cn0) * fastsig(acc0[3]);
        c0 = msk ? cn0 : c0;
        const float h20 = msk ? hn0 : hp0; hp0 = h20;
        const float cn1 = c1 * fastsig(acc1[2] + 1.0f) + fastsig(acc1[0]) * fasttanh(acc1[1]);
        const float hn1 = fasttanh(cn1) * fastsig(acc1[3]);
        c1 = msk ? cn1 : c1;
        const float h21 = msk ? hn1 : hp1; hp1 = h21;

        // (F) pack 4 hc per tile into u64; quad0 stores tile0, quad1 stores tile1
        const unsigned hv0 = f2bf(h20), hv1 = f2bf(h21);
        const int a0 = __shfl((int)hv0, l15, 64),      a1 = __shfl((int)hv0, l15 + 16, 64);
        const int a2 = __shfl((int)hv0, l15 + 32, 64), a3 = __shfl((int)hv0, l15 + 48, 64);
        const int b0 = __shfl((int)hv1, l15, 64),      b1 = __shfl((int)hv1, l15 + 16, 64);
        const int b2 = __shfl((int)hv1, l15 + 32, 64), b3 = __shfl((int)hv1, l15 + 48, 64);
        unsigned short* dstBase = h_all + (size_t)(t + 1) * (B_ * H_) + (size_t)bE * H_
                                + blk * 16 + mpair * 8;
        if (quad == 0){
            const u64 pk = (u64)(unsigned short)a0 | ((u64)(unsigned short)a1 << 16)
                         | ((u64)(unsigned short)a2 << 32) | ((u64)(unsigned short)a3 << 48);
            store8_dev(dstBase, pk);
        } else if (quad == 1){
            const u64 pk = (u64)(unsigned short)b0 | ((u64)(unsigned short)b1 << 16)
                         | ((u64)(unsigned short)b2 << 32) | ((u64)(unsigned short)b3 << 48);
            store8_dev(dstBase + 4, pk);
        }
        wait_vm0();                      // h stores ack'd at the MALL (xe long landed)
        __syncthreads();                 // all waves of block done
        if (tid == 0)
            store4_dev(&flags[blk], (unsigned)(t + 1));

        // (G) tail (in notify slack): 16 MFMA on prefetched bf16 x-row
        if (t + 1 < T_){
            accX0 = (v4f){ bias0[0], bias0[1], bias0[2], bias0[3] };
            accX1 = (v4f){ bias1[0], bias1[1], bias1[2], bias1[3] };
#pragma unroll
            for (int kc = 0; kc < 8; ++kc){
                accX0 = __builtin_amdgcn_mfma_f32_16x16x32_bf16(AW0[kc], xe[kc], accX0, 0, 0, 0);
                accX1 = __builtin_amdgcn_mfma_f32_16x16x32_bf16(AW1[kc], xe[kc], accX1, 0, 0, 0);
            }
        }
        qnext = qnext2;
    }
}

// ---------------------------------------------------------------- projection + relu + log-softmax + xent
__global__ void __launch_bounds__(256) loss_kernel(
    const int* __restrict__ a, const int* __restrict__ lengths,
    const float* __restrict__ projB,
    const unsigned short* __restrict__ h_all,
    const unsigned short* __restrict__ Wt,
    float* __restrict__ out)
{
    const int tid = threadIdx.x;
    const int wv = tid >> 6, lane = tid & 63;
    const int l15 = lane & 15, quad = lane >> 4;
    const int wgid = blockIdx.x * 4 + wv;            // 0..1023
    const int row0 = wgid * 16;

    const int rowA = row0 + l15;
    const int bA = rowA >> 9, tA = rowA & 511;
    const unsigned short* hrow = h_all + ((size_t)(tA + 1) * B_ + bA) * H_;

    v4f acc[4] = { {0,0,0,0}, {0,0,0,0}, {0,0,0,0}, {0,0,0,0} };
#pragma unroll
    for (int kc = 0; kc < 16; ++kc){
        const short8 af = *(const short8*)(hrow + kc * 32 + quad * 8);
#pragma unroll
        for (int ntl = 0; ntl < 4; ++ntl){
            const short8 bf = *(const short8*)(Wt + (size_t)(ntl * 16 + l15) * H_ + kc * 32 + quad * 8);
            acc[ntl] = __builtin_amdgcn_mfma_f32_16x16x32_bf16(af, bf, acc[ntl], 0, 0, 0);
        }
    }

    float pb[4]; bool cv[4];
#pragma unroll
    for (int ntl = 0; ntl < 4; ++ntl){
        const int c = ntl * 16 + l15;
        cv[ntl] = (c < L_);
        pb[ntl] = cv[ntl] ? projB[c] : 0.f;
    }

#pragma unroll
    for (int r = 0; r < 4; ++r){
        const int row = row0 + quad * 4 + r;
        const int b = row >> 9, t = row & 511;
        const int len = lengths[b];
        const bool valid = (t < len);

        float lv[4];
#pragma unroll
        for (int ntl = 0; ntl < 4; ++ntl)
            lv[ntl] = fmaxf(acc[ntl][r] + pb[ntl], 0.f);   // relu(logits)

        float mx = -1e30f;
#pragma unroll
        for (int ntl = 0; ntl < 4; ++ntl) if (cv[ntl]) mx = fmaxf(mx, lv[ntl]);
        mx = qredmax(mx);
        float se = 0.f;
#pragma unroll
        for (int ntl = 0; ntl < 4; ++ntl) if (cv[ntl]) se += expf(lv[ntl] - mx);
        se = qredsum(se);
        const int lbl = a[row];
        float cand = 0.f;
#pragma unroll
        for (int ntl = 0; ntl < 4; ++ntl) if (ntl * 16 + l15 == lbl) cand = lv[ntl];
        const float llbl = qredsum(cand);

        if (valid && l15 == 0){
            const float xent = logf(se) + mx - llbl;      // -log_softmax[label]
            atomicAdd(out, xent / ((float)len * 32.0f));
        }
    }
}

// ---------------------------------------------------------------- launch
extern "C" void kernel_launch(void* const* d_in, const int* in_sizes, int n_in,
                              void* d_out, int out_size, void* d_ws, size_t ws_size,
                              hipStream_t stream)
{
    const int*   q   = (const int*)d_in[0];
    const int*   a   = (const int*)d_in[1];
    const int*   len = (const int*)d_in[2];
    const float* we  = (const float*)d_in[3];
    const float* lW  = (const float*)d_in[4];
    const float* lB  = (const float*)d_in[5];
    const float* pW  = (const float*)d_in[6];
    const float* pB  = (const float*)d_in[7];
    float* out = (float*)d_out;

    unsigned char* ws = (unsigned char*)d_ws;
    unsigned int*   setup = (unsigned int*)ws;                       // 4 KiB (reserved)
    unsigned int*   flags = (unsigned int*)(ws + 4096);              // 32 dwords (4 KiB reserved)
    unsigned short* h_all = (unsigned short*)(ws + 8192);            // 513*32*512*2 B = 16.84 MB
    unsigned short* Wt    = (unsigned short*)(ws + 8192 + (size_t)(T_ + 1) * B_ * H_ * 2);  // 64 KiB
    unsigned short* we_bf = (unsigned short*)(ws + 8192 + (size_t)(T_ + 1) * B_ * H_ * 2 + 65536); // 25.6 MB

    init_kernel<<<dim3(6400), dim3(256), 0, stream>>>(pW, we, out, setup, flags, h_all, Wt, we_bf);

    {
        const int* q_ = q; const int* len_ = len; const unsigned short* we_ = we_bf;
        const float* lW_ = lW; const float* lB_ = lB;
        unsigned short* h_ = h_all; unsigned int* f_ = flags;
        void* args[] = { (void*)&q_, (void*)&len_, (void*)&we_, (void*)&lW_,
                         (void*)&lB_, (void*)&h_, (void*)&f_ };
        hipLaunchCooperativeKernel((void*)lstm_kernel, dim3(NGRID), dim3(256),
                                   args, 0, stream);
    }

    loss_kernel<<<dim3(256), dim3(256), 0, stream>>>(a, len, pB, h_all, Wt, out);
}